// Round 2
// baseline (780.965 us; speedup 1.0000x reference)
//
#include <hip/hip_runtime.h>

#define VOCAB   32000
#define D       128
#define NNODES  50000
#define NEDGES  600000

// ---------------------------------------------------------------------------
// Table MLP: out[r][:] = relu(emb[r][:] @ w + b).
// w (64 KB) in LDS. 256 threads: 4 row-slots (sub) x 64 lanes; each thread
// computes 4 rows x 2 cols = 8 accumulator chains (FMA-latency hiding),
// w_lds reads amortized over 4 rows.
// ---------------------------------------------------------------------------
__global__ __launch_bounds__(256) void mlp_table_kernel(
    const float* __restrict__ emb,
    const float* __restrict__ w,
    const float* __restrict__ b,
    float* __restrict__ outt,
    int rows)
{
    __shared__ float w_lds[D * D];      // 64 KB
    __shared__ float x_lds[16][D];      // 8 KB
    __shared__ float b_lds[D];

    for (int i = threadIdx.x; i < D * D; i += 256) w_lds[i] = w[i];
    if (threadIdx.x < D) b_lds[threadIdx.x] = b[threadIdx.x];

    const int sub  = threadIdx.x >> 6;
    const int lane = threadIdx.x & 63;
    const int c0 = lane, c1 = lane + 64;

    const int rpi   = gridDim.x * 16;                 // rows per iter
    const int iters = (rows + rpi - 1) / rpi;

    for (int it = 0; it < iters; ++it) {
        const int rowbase = (it * gridDim.x + blockIdx.x) * 16;
        __syncthreads();                              // x_lds reuse guard
        for (int v = threadIdx.x; v < 16 * 32; v += 256) {
            const int r = v >> 5, c4 = v & 31;
            const int row = rowbase + r;
            float4 val = (row < rows)
                ? ((const float4*)(emb + (size_t)row * D))[c4]
                : float4{0.f, 0.f, 0.f, 0.f};
            ((float4*)x_lds[r])[c4] = val;
        }
        __syncthreads();

        float acc[4][2];
        #pragma unroll
        for (int j = 0; j < 4; ++j) { acc[j][0] = b_lds[c0]; acc[j][1] = b_lds[c1]; }

        #pragma unroll
        for (int k = 0; k < D; ++k) {
            const float w0 = w_lds[k * D + c0];
            const float w1 = w_lds[k * D + c1];
            #pragma unroll
            for (int j = 0; j < 4; ++j) {
                const float xv = x_lds[sub * 4 + j][k];
                acc[j][0] = fmaf(xv, w0, acc[j][0]);
                acc[j][1] = fmaf(xv, w1, acc[j][1]);
            }
        }
        #pragma unroll
        for (int j = 0; j < 4; ++j) {
            const int row = rowbase + sub * 4 + j;
            if (row < rows) {
                float* o = outt + (size_t)row * D;
                o[c0] = fmaxf(acc[j][0], 0.f);
                o[c1] = fmaxf(acc[j][1], 0.f);
            }
        }
    }
}

// ---------------------------------------------------------------------------
// CSR build: histogram of dst, single-block scan, scatter of (tn, te) pairs.
// ---------------------------------------------------------------------------
__global__ __launch_bounds__(256) void hist_kernel(
    const int* __restrict__ dstv, int* __restrict__ counts, int n)
{
    int e = blockIdx.x * 256 + threadIdx.x;
    if (e < n) atomicAdd(&counts[dstv[e]], 1);
}

__global__ __launch_bounds__(1024) void scan_kernel(
    const int* __restrict__ counts,
    int* __restrict__ offsets,
    int* __restrict__ cursor)
{
    __shared__ int part[1024];
    const int C = (NNODES + 1023) / 1024;   // 49
    const int t = threadIdx.x;
    const int base = t * C;

    int s = 0;
    for (int i = 0; i < C; ++i) {
        const int idx = base + i;
        if (idx < NNODES) s += counts[idx];
    }
    part[t] = s;
    __syncthreads();
    for (int off = 1; off < 1024; off <<= 1) {
        int v = (t >= off) ? part[t - off] : 0;
        __syncthreads();
        part[t] += v;
        __syncthreads();
    }
    int run = (t == 0) ? 0 : part[t - 1];
    for (int i = 0; i < C; ++i) {
        const int idx = base + i;
        if (idx < NNODES) {
            offsets[idx] = run;
            cursor[idx]  = run;
            run += counts[idx];
        }
    }
    if (t == 1023) offsets[NNODES] = part[1023];
}

__global__ __launch_bounds__(256) void scatter_kernel(
    const int* __restrict__ srcv, const int* __restrict__ dstv,
    const int* __restrict__ node_tokens, const int* __restrict__ edge_tokens,
    int* __restrict__ cursor, int2* __restrict__ pairs, int n)
{
    int e = blockIdx.x * 256 + threadIdx.x;
    if (e >= n) return;
    const int d = dstv[e];
    const int p = atomicAdd(&cursor[d], 1);
    pairs[p] = make_int2(node_tokens[srcv[e]], edge_tokens[e]);
}

// ---------------------------------------------------------------------------
// Gather: one wave per node. Lanes cooperatively prefetch up to 64 (tn,te)
// pairs, broadcast via shuffle, accumulate t1[tn]*t2[te] in registers,
// write the output row once (coalesced float2). No atomics anywhere.
// ---------------------------------------------------------------------------
__global__ __launch_bounds__(256) void gather_kernel(
    const float* __restrict__ t1, const float* __restrict__ t2,
    const int* __restrict__ offsets, const int2* __restrict__ pairs,
    float* __restrict__ outp)
{
    const int wid = (blockIdx.x * 256 + threadIdx.x) >> 6;
    if (wid >= NNODES) return;
    const int lane = threadIdx.x & 63;

    const int beg = offsets[wid];
    const int end = offsets[wid + 1];

    float2 acc = {0.f, 0.f};
    for (int base = beg; base < end; base += 64) {
        const int m = min(64, end - base);
        int2 pr = (lane < m) ? pairs[base + lane] : make_int2(0, 0);
        for (int i = 0; i < m; ++i) {
            const int tn = __shfl(pr.x, i);
            const int te = __shfl(pr.y, i);
            const float2 a  = ((const float2*)(t1 + (size_t)tn * D))[lane];
            const float2 bb = ((const float2*)(t2 + (size_t)te * D))[lane];
            acc.x = fmaf(a.x, bb.x, acc.x);
            acc.y = fmaf(a.y, bb.y, acc.y);
        }
    }
    ((float2*)(outp + (size_t)wid * D))[lane] = acc;
}

extern "C" void kernel_launch(void* const* d_in, const int* in_sizes, int n_in,
                              void* d_out, int out_size, void* d_ws, size_t ws_size,
                              hipStream_t stream) {
    const float* emb = (const float*)d_in[0];
    const float* w1  = (const float*)d_in[1];
    const float* b1  = (const float*)d_in[2];
    const float* w2  = (const float*)d_in[3];
    const float* b2  = (const float*)d_in[4];
    const int* node_tokens = (const int*)d_in[5];
    const int* edge_tokens = (const int*)d_in[6];
    const int* src = (const int*)d_in[7];
    const int* dst = (const int*)d_in[8];
    float* out = (float*)d_out;

    // workspace layout (bytes):
    //   t1:      [0, 16,384,000)
    //   t2:      [16,384,000, 32,768,000)
    //   pairs:   [32,768,000, 37,568,000)   int2 x NEDGES
    //   counts:  [37,568,000, 37,768,000)
    //   offsets: [37,768,000, 37,968,016)
    //   cursor:  [37,968,016, 38,168,016)
    char* wsb = (char*)d_ws;
    float* t1     = (float*)(wsb);
    float* t2     = (float*)(wsb + 16384000);
    int2*  pairs  = (int2*) (wsb + 32768000);
    int*   counts = (int*)  (wsb + 37568000);
    int*   offs   = (int*)  (wsb + 37768000);
    int*   cursor = (int*)  (wsb + 37968016);

    hipMemsetAsync(counts, 0, NNODES * sizeof(int), stream);

    // table MLPs: 500 blocks x 16 rows x 4 iters = 32000 rows
    mlp_table_kernel<<<500, 256, 0, stream>>>(emb, w1, b1, t1, VOCAB);
    mlp_table_kernel<<<500, 256, 0, stream>>>(emb, w2, b2, t2, VOCAB);

    // CSR build
    hist_kernel<<<(NEDGES + 255) / 256, 256, 0, stream>>>(dst, counts, NEDGES);
    scan_kernel<<<1, 1024, 0, stream>>>(counts, offs, cursor);
    scatter_kernel<<<(NEDGES + 255) / 256, 256, 0, stream>>>(
        src, dst, node_tokens, edge_tokens, cursor, pairs, NEDGES);

    // aggregate: 1 wave per node, no atomics, writes every output row
    gather_kernel<<<(NNODES + 3) / 4, 256, 0, stream>>>(t1, t2, offs, pairs, out);
}

// Round 3
// 408.334 us; speedup vs baseline: 1.9126x; 1.9126x over previous
//
#include <hip/hip_runtime.h>

#define VOCAB   32000
#define D       128
#define NNODES  50000
#define NEDGES  600000

// ---------------------------------------------------------------------------
// Table MLP: out[r][:] = relu(emb[r][:] @ w + b) for 32000 rows.
// wT in LDS, XOR-swizzled per 16B group (g ^= c&7) -> ds_read_b128 per col.
// x rows read from global with wave-uniform addresses (s_load path).
// 256 thr = 4 waves; wave handles 4 rows x (c0=lane, c1=lane+64).
// Grid 500, 4 iters: 500*4*16 = 32000 rows exactly.
// ---------------------------------------------------------------------------
__global__ __launch_bounds__(256) void mlp_table_kernel(
    const float* __restrict__ emb,
    const float* __restrict__ w,
    const float* __restrict__ b,
    float* __restrict__ outt)
{
    __shared__ __align__(16) float wT[D * D];   // 64 KB, swizzled transpose

    // transpose w[k][c] -> wT[c][swz(k)]
    {
        const int k0 = threadIdx.x >> 5;          // 0..7
        const int c4 = (threadIdx.x & 31) * 4;    // 0..124
        for (int kk = 0; kk < D; kk += 8) {
            const int k = kk + k0;
            const float4 v = *(const float4*)(w + (size_t)k * D + c4);
            const float vv[4] = {v.x, v.y, v.z, v.w};
            #pragma unroll
            for (int j = 0; j < 4; ++j) {
                const int c = c4 + j;
                const int g = (k >> 2) ^ (c & 7);
                wT[c * D + g * 4 + (k & 3)] = vv[j];
            }
        }
    }

    const int lane = threadIdx.x & 63;
    const int sub  = threadIdx.x >> 6;
    const int c0 = lane, c1 = lane + 64;
    const float b0 = b[c0], b1 = b[c1];
    const int s0 = (c0 & 7), s1 = (c1 & 7);
    __syncthreads();

    for (int it = 0; it < 4; ++it) {
        const int rowbase = __builtin_amdgcn_readfirstlane(
            (it * 500 + blockIdx.x) * 16 + sub * 4);
        const float* __restrict__ x0 = emb + (size_t)rowbase * D;

        float acc[4][2];
        #pragma unroll
        for (int j = 0; j < 4; ++j) { acc[j][0] = b0; acc[j][1] = b1; }

        #pragma unroll 2
        for (int kc = 0; kc < 16; ++kc) {         // 8 k per chunk
            const int g0 = kc * 2, g1 = kc * 2 + 1;
            const float4 w0a = *(const float4*)&wT[c0 * D + ((g0 ^ s0) << 2)];
            const float4 w0b = *(const float4*)&wT[c0 * D + ((g1 ^ s0) << 2)];
            const float4 w1a = *(const float4*)&wT[c1 * D + ((g0 ^ s1) << 2)];
            const float4 w1b = *(const float4*)&wT[c1 * D + ((g1 ^ s1) << 2)];
            #pragma unroll
            for (int j = 0; j < 4; ++j) {
                const float* __restrict__ xr = x0 + j * D + kc * 8;
                const float4 xa = *(const float4*)(xr);
                const float4 xb = *(const float4*)(xr + 4);
                acc[j][0] = fmaf(xa.x, w0a.x, acc[j][0]);
                acc[j][1] = fmaf(xa.x, w1a.x, acc[j][1]);
                acc[j][0] = fmaf(xa.y, w0a.y, acc[j][0]);
                acc[j][1] = fmaf(xa.y, w1a.y, acc[j][1]);
                acc[j][0] = fmaf(xa.z, w0a.z, acc[j][0]);
                acc[j][1] = fmaf(xa.z, w1a.z, acc[j][1]);
                acc[j][0] = fmaf(xa.w, w0a.w, acc[j][0]);
                acc[j][1] = fmaf(xa.w, w1a.w, acc[j][1]);
                acc[j][0] = fmaf(xb.x, w0b.x, acc[j][0]);
                acc[j][1] = fmaf(xb.x, w1b.x, acc[j][1]);
                acc[j][0] = fmaf(xb.y, w0b.y, acc[j][0]);
                acc[j][1] = fmaf(xb.y, w1b.y, acc[j][1]);
                acc[j][0] = fmaf(xb.z, w0b.z, acc[j][0]);
                acc[j][1] = fmaf(xb.z, w1b.z, acc[j][1]);
                acc[j][0] = fmaf(xb.w, w0b.w, acc[j][0]);
                acc[j][1] = fmaf(xb.w, w1b.w, acc[j][1]);
            }
        }
        #pragma unroll
        for (int j = 0; j < 4; ++j) {
            float* o = outt + (size_t)(rowbase + j) * D;
            o[c0] = fmaxf(acc[j][0], 0.f);
            o[c1] = fmaxf(acc[j][1], 0.f);
        }
    }
}

// ---------------------------------------------------------------------------
// CSR build
// ---------------------------------------------------------------------------
__global__ __launch_bounds__(256) void hist_kernel(
    const int4* __restrict__ dst4, int* __restrict__ counts)
{
    const int t = blockIdx.x * 256 + threadIdx.x;
    if (t < NEDGES / 4) {
        const int4 d = dst4[t];
        atomicAdd(&counts[d.x], 1);
        atomicAdd(&counts[d.y], 1);
        atomicAdd(&counts[d.z], 1);
        atomicAdd(&counts[d.w], 1);
    }
}

__global__ __launch_bounds__(1024) void scan_kernel(
    const int* __restrict__ counts,
    int* __restrict__ offsets,
    int* __restrict__ cursor)
{
    __shared__ int part[1024];
    const int C = (NNODES + 1023) / 1024;   // 49
    const int t = threadIdx.x;
    const int base = t * C;

    int s = 0;
    for (int i = 0; i < C; ++i) {
        const int idx = base + i;
        if (idx < NNODES) s += counts[idx];
    }
    part[t] = s;
    __syncthreads();
    for (int off = 1; off < 1024; off <<= 1) {
        int v = (t >= off) ? part[t - off] : 0;
        __syncthreads();
        part[t] += v;
        __syncthreads();
    }
    int run = (t == 0) ? 0 : part[t - 1];
    for (int i = 0; i < C; ++i) {
        const int idx = base + i;
        if (idx < NNODES) {
            offsets[idx] = run;
            cursor[idx]  = run;
            run += counts[idx];
        }
    }
    if (t == 1023) offsets[NNODES] = part[1023];
}

__global__ __launch_bounds__(256) void scatter_kernel(
    const int4* __restrict__ src4, const int4* __restrict__ dst4,
    const int* __restrict__ node_tokens, const int4* __restrict__ et4,
    int* __restrict__ cursor, int2* __restrict__ pairs)
{
    const int t = blockIdx.x * 256 + threadIdx.x;
    if (t >= NEDGES / 4) return;
    const int4 s = src4[t];
    const int4 d = dst4[t];
    const int4 te = et4[t];
    int p;
    p = atomicAdd(&cursor[d.x], 1); pairs[p] = make_int2(node_tokens[s.x], te.x);
    p = atomicAdd(&cursor[d.y], 1); pairs[p] = make_int2(node_tokens[s.y], te.y);
    p = atomicAdd(&cursor[d.z], 1); pairs[p] = make_int2(node_tokens[s.z], te.z);
    p = atomicAdd(&cursor[d.w], 1); pairs[p] = make_int2(node_tokens[s.w], te.w);
}

// ---------------------------------------------------------------------------
// Gather: one wave per node; half-wave edge parallelism.
// Lanes 0-31 process even-indexed edges, 32-63 odd; float4 per sublane
// covers a 512B row; one shfl_xor(32) combine; single coalesced row write.
// ---------------------------------------------------------------------------
__global__ __launch_bounds__(256) void gather_kernel(
    const float* __restrict__ t1, const float* __restrict__ t2,
    const int* __restrict__ offsets, const int2* __restrict__ pairs,
    float* __restrict__ outp)
{
    const int wid = (blockIdx.x * 256 + threadIdx.x) >> 6;
    if (wid >= NNODES) return;
    const int lane = threadIdx.x & 63;
    const int half = lane >> 5;
    const int sl   = lane & 31;

    const int beg = offsets[wid];
    const int end = offsets[wid + 1];

    float4 acc = {0.f, 0.f, 0.f, 0.f};
    for (int base = beg; base < end; base += 64) {
        const int m = min(64, end - base);
        int2 pr = (lane < m) ? pairs[base + lane] : make_int2(0, 0);
        for (int j = half; j < m; j += 2) {
            const int tn = __shfl(pr.x, j);
            const int te = __shfl(pr.y, j);
            const float4 a  = ((const float4*)(t1 + (size_t)tn * D))[sl];
            const float4 bb = ((const float4*)(t2 + (size_t)te * D))[sl];
            acc.x = fmaf(a.x, bb.x, acc.x);
            acc.y = fmaf(a.y, bb.y, acc.y);
            acc.z = fmaf(a.z, bb.z, acc.z);
            acc.w = fmaf(a.w, bb.w, acc.w);
        }
    }
    acc.x += __shfl_xor(acc.x, 32);
    acc.y += __shfl_xor(acc.y, 32);
    acc.z += __shfl_xor(acc.z, 32);
    acc.w += __shfl_xor(acc.w, 32);
    if (half == 0)
        ((float4*)(outp + (size_t)wid * D))[sl] = acc;
}

extern "C" void kernel_launch(void* const* d_in, const int* in_sizes, int n_in,
                              void* d_out, int out_size, void* d_ws, size_t ws_size,
                              hipStream_t stream) {
    const float* emb = (const float*)d_in[0];
    const float* w1  = (const float*)d_in[1];
    const float* b1  = (const float*)d_in[2];
    const float* w2  = (const float*)d_in[3];
    const float* b2  = (const float*)d_in[4];
    const int* node_tokens = (const int*)d_in[5];
    const int* edge_tokens = (const int*)d_in[6];
    const int* src = (const int*)d_in[7];
    const int* dst = (const int*)d_in[8];
    float* out = (float*)d_out;

    // workspace layout (bytes)
    char* wsb = (char*)d_ws;
    float* t1     = (float*)(wsb);                 // 16,384,000
    float* t2     = (float*)(wsb + 16384000);      // 16,384,000
    int2*  pairs  = (int2*) (wsb + 32768000);      //  4,800,000
    int*   counts = (int*)  (wsb + 37568000);      //    200,000
    int*   offs   = (int*)  (wsb + 37768000);      //    200,004
    int*   cursor = (int*)  (wsb + 37968016);      //    200,000

    hipMemsetAsync(counts, 0, NNODES * sizeof(int), stream);

    mlp_table_kernel<<<500, 256, 0, stream>>>(emb, w1, b1, t1);
    mlp_table_kernel<<<500, 256, 0, stream>>>(emb, w2, b2, t2);

    hist_kernel<<<(NEDGES / 4 + 255) / 256, 256, 0, stream>>>(
        (const int4*)dst, counts);
    scan_kernel<<<1, 1024, 0, stream>>>(counts, offs, cursor);
    scatter_kernel<<<(NEDGES / 4 + 255) / 256, 256, 0, stream>>>(
        (const int4*)src, (const int4*)dst, node_tokens,
        (const int4*)edge_tokens, cursor, pairs);

    gather_kernel<<<(NNODES + 3) / 4, 256, 0, stream>>>(t1, t2, offs, pairs, out);
}

// Round 4
// 287.822 us; speedup vs baseline: 2.7134x; 1.4187x over previous
//
#include <hip/hip_runtime.h>

#define VOCAB   32000
#define D       128
#define NNODES  50000
#define NEDGES  600000

// ---------------------------------------------------------------------------
// Table MLP: out[r][:] = relu(emb[r][:] @ w + b) for 32000 rows.
// wT in LDS, XOR-swizzled per 16B group (g ^= c&7) -> ds_read_b128 per col.
// x rows read from global with wave-uniform addresses (s_load path).
// ---------------------------------------------------------------------------
__global__ __launch_bounds__(256) void mlp_table_kernel(
    const float* __restrict__ emb,
    const float* __restrict__ w,
    const float* __restrict__ b,
    float* __restrict__ outt)
{
    __shared__ __align__(16) float wT[D * D];   // 64 KB, swizzled transpose

    {
        const int k0 = threadIdx.x >> 5;          // 0..7
        const int c4 = (threadIdx.x & 31) * 4;    // 0..124
        for (int kk = 0; kk < D; kk += 8) {
            const int k = kk + k0;
            const float4 v = *(const float4*)(w + (size_t)k * D + c4);
            const float vv[4] = {v.x, v.y, v.z, v.w};
            #pragma unroll
            for (int j = 0; j < 4; ++j) {
                const int c = c4 + j;
                const int g = (k >> 2) ^ (c & 7);
                wT[c * D + g * 4 + (k & 3)] = vv[j];
            }
        }
    }

    const int lane = threadIdx.x & 63;
    const int sub  = threadIdx.x >> 6;
    const int c0 = lane, c1 = lane + 64;
    const float b0 = b[c0], b1 = b[c1];
    const int s0 = (c0 & 7), s1 = (c1 & 7);
    __syncthreads();

    for (int it = 0; it < 4; ++it) {
        const int rowbase = __builtin_amdgcn_readfirstlane(
            (it * 500 + blockIdx.x) * 16 + sub * 4);
        const float* __restrict__ x0 = emb + (size_t)rowbase * D;

        float acc[4][2];
        #pragma unroll
        for (int j = 0; j < 4; ++j) { acc[j][0] = b0; acc[j][1] = b1; }

        #pragma unroll 2
        for (int kc = 0; kc < 16; ++kc) {         // 8 k per chunk
            const int g0 = kc * 2, g1 = kc * 2 + 1;
            const float4 w0a = *(const float4*)&wT[c0 * D + ((g0 ^ s0) << 2)];
            const float4 w0b = *(const float4*)&wT[c0 * D + ((g1 ^ s0) << 2)];
            const float4 w1a = *(const float4*)&wT[c1 * D + ((g0 ^ s1) << 2)];
            const float4 w1b = *(const float4*)&wT[c1 * D + ((g1 ^ s1) << 2)];
            #pragma unroll
            for (int j = 0; j < 4; ++j) {
                const float* __restrict__ xr = x0 + j * D + kc * 8;
                const float4 xa = *(const float4*)(xr);
                const float4 xb = *(const float4*)(xr + 4);
                acc[j][0] = fmaf(xa.x, w0a.x, acc[j][0]);
                acc[j][1] = fmaf(xa.x, w1a.x, acc[j][1]);
                acc[j][0] = fmaf(xa.y, w0a.y, acc[j][0]);
                acc[j][1] = fmaf(xa.y, w1a.y, acc[j][1]);
                acc[j][0] = fmaf(xa.z, w0a.z, acc[j][0]);
                acc[j][1] = fmaf(xa.z, w1a.z, acc[j][1]);
                acc[j][0] = fmaf(xa.w, w0a.w, acc[j][0]);
                acc[j][1] = fmaf(xa.w, w1a.w, acc[j][1]);
                acc[j][0] = fmaf(xb.x, w0b.x, acc[j][0]);
                acc[j][1] = fmaf(xb.x, w1b.x, acc[j][1]);
                acc[j][0] = fmaf(xb.y, w0b.y, acc[j][0]);
                acc[j][1] = fmaf(xb.y, w1b.y, acc[j][1]);
                acc[j][0] = fmaf(xb.z, w0b.z, acc[j][0]);
                acc[j][1] = fmaf(xb.z, w1b.z, acc[j][1]);
                acc[j][0] = fmaf(xb.w, w0b.w, acc[j][0]);
                acc[j][1] = fmaf(xb.w, w1b.w, acc[j][1]);
            }
        }
        #pragma unroll
        for (int j = 0; j < 4; ++j) {
            float* o = outt + (size_t)(rowbase + j) * D;
            o[c0] = fmaxf(acc[j][0], 0.f);
            o[c1] = fmaxf(acc[j][1], 0.f);
        }
    }
}

// ---------------------------------------------------------------------------
// CSR build
// ---------------------------------------------------------------------------
__global__ __launch_bounds__(256) void hist_kernel(
    const int4* __restrict__ dst4, int* __restrict__ counts)
{
    const int t = blockIdx.x * 256 + threadIdx.x;
    if (t < NEDGES / 4) {
        const int4 d = dst4[t];
        atomicAdd(&counts[d.x], 1);
        atomicAdd(&counts[d.y], 1);
        atomicAdd(&counts[d.z], 1);
        atomicAdd(&counts[d.w], 1);
    }
}

// phase 1: per-block exclusive scan (into offs) + per-block totals
__global__ __launch_bounds__(256) void scan_phase1(
    const int* __restrict__ counts,
    int* __restrict__ offs,
    int* __restrict__ btot)
{
    const int i    = blockIdx.x * 256 + threadIdx.x;
    const int lane = threadIdx.x & 63;
    const int wv   = threadIdx.x >> 6;

    const int v = (i < NNODES) ? counts[i] : 0;
    int inc = v;
    #pragma unroll
    for (int off = 1; off < 64; off <<= 1) {
        int u = __shfl_up(inc, off);
        if (lane >= off) inc += u;
    }
    __shared__ int wtot[4];
    if (lane == 63) wtot[wv] = inc;
    __syncthreads();
    int wpre = 0;
    #pragma unroll
    for (int k = 0; k < 3; ++k) if (k < wv) wpre += wtot[k];
    inc += wpre;
    if (i < NNODES) offs[i] = inc - v;               // exclusive, block-local
    if (threadIdx.x == 255) btot[blockIdx.x] = inc;  // block total
}

// phase 2: add block prefix in-place; mirror into cursor; offs[N] = NEDGES
__global__ __launch_bounds__(256) void scan_phase2(
    const int* __restrict__ btot,
    int* __restrict__ offs,
    int* __restrict__ cursor,
    int nblocks)
{
    const int t    = threadIdx.x;
    const int lane = t & 63;
    const int wv   = t >> 6;

    int v = (t < blockIdx.x && t < nblocks) ? btot[t] : 0;  // nblocks<=256
    #pragma unroll
    for (int off = 32; off > 0; off >>= 1) v += __shfl_xor(v, off);
    __shared__ int ws[4];
    if (lane == 0) ws[wv] = v;
    __syncthreads();
    const int bpre = ws[0] + ws[1] + ws[2] + ws[3];

    const int i = blockIdx.x * 256 + t;
    if (i < NNODES) {
        const int o = offs[i] + bpre;
        offs[i]   = o;
        cursor[i] = o;
    }
    if (blockIdx.x == 0 && t == 0) offs[NNODES] = NEDGES;
}

__global__ __launch_bounds__(256) void scatter_kernel(
    const int4* __restrict__ src4, const int4* __restrict__ dst4,
    const int* __restrict__ node_tokens, const int4* __restrict__ et4,
    int* __restrict__ cursor, int2* __restrict__ pairs)
{
    const int t = blockIdx.x * 256 + threadIdx.x;
    if (t >= NEDGES / 4) return;
    const int4 s = src4[t];
    const int4 d = dst4[t];
    const int4 te = et4[t];
    int p;
    p = atomicAdd(&cursor[d.x], 1); pairs[p] = make_int2(node_tokens[s.x], te.x);
    p = atomicAdd(&cursor[d.y], 1); pairs[p] = make_int2(node_tokens[s.y], te.y);
    p = atomicAdd(&cursor[d.z], 1); pairs[p] = make_int2(node_tokens[s.z], te.z);
    p = atomicAdd(&cursor[d.w], 1); pairs[p] = make_int2(node_tokens[s.w], te.w);
}

// ---------------------------------------------------------------------------
// Gather: one wave per node; half-wave edge parallelism; no atomics.
// ---------------------------------------------------------------------------
__global__ __launch_bounds__(256) void gather_kernel(
    const float* __restrict__ t1, const float* __restrict__ t2,
    const int* __restrict__ offsets, const int2* __restrict__ pairs,
    float* __restrict__ outp)
{
    const int wid = (blockIdx.x * 256 + threadIdx.x) >> 6;
    if (wid >= NNODES) return;
    const int lane = threadIdx.x & 63;
    const int half = lane >> 5;
    const int sl   = lane & 31;

    const int beg = offsets[wid];
    const int end = offsets[wid + 1];

    float4 acc = {0.f, 0.f, 0.f, 0.f};
    for (int base = beg; base < end; base += 64) {
        const int m = min(64, end - base);
        int2 pr = (lane < m) ? pairs[base + lane] : make_int2(0, 0);
        for (int j = half; j < m; j += 2) {
            const int tn = __shfl(pr.x, j);
            const int te = __shfl(pr.y, j);
            const float4 a  = ((const float4*)(t1 + (size_t)tn * D))[sl];
            const float4 bb = ((const float4*)(t2 + (size_t)te * D))[sl];
            acc.x = fmaf(a.x, bb.x, acc.x);
            acc.y = fmaf(a.y, bb.y, acc.y);
            acc.z = fmaf(a.z, bb.z, acc.z);
            acc.w = fmaf(a.w, bb.w, acc.w);
        }
    }
    acc.x += __shfl_xor(acc.x, 32);
    acc.y += __shfl_xor(acc.y, 32);
    acc.z += __shfl_xor(acc.z, 32);
    acc.w += __shfl_xor(acc.w, 32);
    if (half == 0)
        ((float4*)(outp + (size_t)wid * D))[sl] = acc;
}

extern "C" void kernel_launch(void* const* d_in, const int* in_sizes, int n_in,
                              void* d_out, int out_size, void* d_ws, size_t ws_size,
                              hipStream_t stream) {
    const float* emb = (const float*)d_in[0];
    const float* w1  = (const float*)d_in[1];
    const float* b1  = (const float*)d_in[2];
    const float* w2  = (const float*)d_in[3];
    const float* b2  = (const float*)d_in[4];
    const int* node_tokens = (const int*)d_in[5];
    const int* edge_tokens = (const int*)d_in[6];
    const int* src = (const int*)d_in[7];
    const int* dst = (const int*)d_in[8];
    float* out = (float*)d_out;

    // workspace layout (bytes)
    char* wsb = (char*)d_ws;
    float* t1     = (float*)(wsb);                 // 16,384,000
    float* t2     = (float*)(wsb + 16384000);      // 16,384,000
    int2*  pairs  = (int2*) (wsb + 32768000);      //  4,800,000
    int*   counts = (int*)  (wsb + 37568000);      //    200,000
    int*   offs   = (int*)  (wsb + 37768000);      //    200,004
    int*   cursor = (int*)  (wsb + 37968016);      //    200,000
    int*   btot   = (int*)  (wsb + 38168016);      //        784

    hipMemsetAsync(counts, 0, NNODES * sizeof(int), stream);

    mlp_table_kernel<<<500, 256, 0, stream>>>(emb, w1, b1, t1);
    mlp_table_kernel<<<500, 256, 0, stream>>>(emb, w2, b2, t2);

    const int nscan = (NNODES + 255) / 256;        // 196
    hist_kernel<<<(NEDGES / 4 + 255) / 256, 256, 0, stream>>>(
        (const int4*)dst, counts);
    scan_phase1<<<nscan, 256, 0, stream>>>(counts, offs, btot);
    scan_phase2<<<nscan, 256, 0, stream>>>(btot, offs, cursor, nscan);
    scatter_kernel<<<(NEDGES / 4 + 255) / 256, 256, 0, stream>>>(
        (const int4*)src, (const int4*)dst, node_tokens,
        (const int4*)edge_tokens, cursor, pairs);

    gather_kernel<<<(NNODES + 3) / 4, 256, 0, stream>>>(t1, t2, offs, pairs, out);
}

// Round 6
// 242.766 us; speedup vs baseline: 3.2169x; 1.1856x over previous
//
#include <hip/hip_runtime.h>

#define VOCAB   32000
#define D       128
#define NNODES  50000
#define NEDGES  600000

typedef unsigned short ushort_t;
typedef unsigned int   uint_t;

__device__ __forceinline__ float bf2f(ushort_t u) {
    union { uint_t i; float f; } c; c.i = ((uint_t)u) << 16; return c.f;
}
__device__ __forceinline__ ushort_t f2bf(float f) {
    union { float f; uint_t i; } c; c.f = f;
    uint_t u = c.i;
    u += 0x7fff + ((u >> 16) & 1);            // round-to-nearest-even
    return (ushort_t)(u >> 16);
}

// ---------------------------------------------------------------------------
// Fused: dst-histogram slice (600 edges/block, overlapped) + table MLP.
// Blocks [0,500) -> table1(w1,b1), [500,1000) -> table2(w2,b2).
// wT in LDS, XOR-swizzled per 16B group (g ^= c&7) -> ds_read_b128 per col.
// Output stored as bf16 (f32 accumulate).
// ---------------------------------------------------------------------------
__global__ __launch_bounds__(256) void mlp_hist_kernel(
    const float* __restrict__ emb,
    const float* __restrict__ w1, const float* __restrict__ b1,
    const float* __restrict__ w2, const float* __restrict__ b2,
    ushort_t* __restrict__ t1, ushort_t* __restrict__ t2,
    const int* __restrict__ dstv, int* __restrict__ counts)
{
    // histogram slice: fire-and-forget atomics, hidden under the GEMM
    {
        const int base = blockIdx.x * (NEDGES / 1000);   // 600/block
        for (int i = base + threadIdx.x; i < base + NEDGES / 1000; i += 256)
            atomicAdd(&counts[dstv[i]], 1);
    }

    const int tab = (blockIdx.x >= 500) ? 1 : 0;
    const float* __restrict__ w = tab ? w2 : w1;
    const float* __restrict__ b = tab ? b2 : b1;
    ushort_t* __restrict__ outt = tab ? t2 : t1;
    const int bid = blockIdx.x - tab * 500;

    __shared__ __align__(16) float wT[D * D];   // 64 KB, swizzled transpose

    {
        const int k0 = threadIdx.x >> 5;          // 0..7
        const int c4 = (threadIdx.x & 31) * 4;    // 0..124
        for (int kk = 0; kk < D; kk += 8) {
            const int k = kk + k0;
            const float4 v = *(const float4*)(w + (size_t)k * D + c4);
            const float vv[4] = {v.x, v.y, v.z, v.w};
            #pragma unroll
            for (int j = 0; j < 4; ++j) {
                const int c = c4 + j;
                const int g = (k >> 2) ^ (c & 7);
                wT[c * D + g * 4 + (k & 3)] = vv[j];
            }
        }
    }

    const int lane = threadIdx.x & 63;
    const int sub  = threadIdx.x >> 6;
    const int c0 = lane, c1 = lane + 64;
    const float bb0 = b[c0], bb1 = b[c1];
    const int s0 = (c0 & 7), s1 = (c1 & 7);
    __syncthreads();

    for (int it = 0; it < 4; ++it) {
        const int rowbase = __builtin_amdgcn_readfirstlane(
            (it * 500 + bid) * 16 + sub * 4);
        const float* __restrict__ x0 = emb + (size_t)rowbase * D;

        float acc[4][2];
        #pragma unroll
        for (int j = 0; j < 4; ++j) { acc[j][0] = bb0; acc[j][1] = bb1; }

        #pragma unroll 2
        for (int kc = 0; kc < 16; ++kc) {         // 8 k per chunk
            const int g0 = kc * 2, g1 = kc * 2 + 1;
            const float4 w0a = *(const float4*)&wT[c0 * D + ((g0 ^ s0) << 2)];
            const float4 w0b = *(const float4*)&wT[c0 * D + ((g1 ^ s0) << 2)];
            const float4 w1a = *(const float4*)&wT[c1 * D + ((g0 ^ s1) << 2)];
            const float4 w1b = *(const float4*)&wT[c1 * D + ((g1 ^ s1) << 2)];
            #pragma unroll
            for (int j = 0; j < 4; ++j) {
                const float* __restrict__ xr = x0 + j * D + kc * 8;
                const float4 xa = *(const float4*)(xr);
                const float4 xb = *(const float4*)(xr + 4);
                acc[j][0] = fmaf(xa.x, w0a.x, acc[j][0]);
                acc[j][1] = fmaf(xa.x, w1a.x, acc[j][1]);
                acc[j][0] = fmaf(xa.y, w0a.y, acc[j][0]);
                acc[j][1] = fmaf(xa.y, w1a.y, acc[j][1]);
                acc[j][0] = fmaf(xa.z, w0a.z, acc[j][0]);
                acc[j][1] = fmaf(xa.z, w1a.z, acc[j][1]);
                acc[j][0] = fmaf(xa.w, w0a.w, acc[j][0]);
                acc[j][1] = fmaf(xa.w, w1a.w, acc[j][1]);
                acc[j][0] = fmaf(xb.x, w0b.x, acc[j][0]);
                acc[j][1] = fmaf(xb.x, w1b.x, acc[j][1]);
                acc[j][0] = fmaf(xb.y, w0b.y, acc[j][0]);
                acc[j][1] = fmaf(xb.y, w1b.y, acc[j][1]);
                acc[j][0] = fmaf(xb.z, w0b.z, acc[j][0]);
                acc[j][1] = fmaf(xb.z, w1b.z, acc[j][1]);
                acc[j][0] = fmaf(xb.w, w0b.w, acc[j][0]);
                acc[j][1] = fmaf(xb.w, w1b.w, acc[j][1]);
            }
        }
        #pragma unroll
        for (int j = 0; j < 4; ++j) {
            ushort_t* o = outt + (size_t)(rowbase + j) * D;
            o[c0] = f2bf(fmaxf(acc[j][0], 0.f));
            o[c1] = f2bf(fmaxf(acc[j][1], 0.f));
        }
    }
}

// ---------------------------------------------------------------------------
// Hierarchical scan (phase1: per-block excl scan + totals; phase2: add prefix)
// ---------------------------------------------------------------------------
__global__ __launch_bounds__(256) void scan_phase1(
    const int* __restrict__ counts,
    int* __restrict__ offs,
    int* __restrict__ btot)
{
    const int i    = blockIdx.x * 256 + threadIdx.x;
    const int lane = threadIdx.x & 63;
    const int wv   = threadIdx.x >> 6;

    const int v = (i < NNODES) ? counts[i] : 0;
    int inc = v;
    #pragma unroll
    for (int off = 1; off < 64; off <<= 1) {
        int u = __shfl_up(inc, off);
        if (lane >= off) inc += u;
    }
    __shared__ int wtot[4];
    if (lane == 63) wtot[wv] = inc;
    __syncthreads();
    int wpre = 0;
    #pragma unroll
    for (int k = 0; k < 3; ++k) if (k < wv) wpre += wtot[k];
    inc += wpre;
    if (i < NNODES) offs[i] = inc - v;
    if (threadIdx.x == 255) btot[blockIdx.x] = inc;
}

__global__ __launch_bounds__(256) void scan_phase2(
    const int* __restrict__ btot,
    int* __restrict__ offs,
    int* __restrict__ cursor,
    int nblocks)
{
    const int t    = threadIdx.x;
    const int lane = t & 63;
    const int wv   = t >> 6;

    int v = (t < blockIdx.x && t < nblocks) ? btot[t] : 0;
    #pragma unroll
    for (int off = 32; off > 0; off >>= 1) v += __shfl_xor(v, off);
    __shared__ int ws[4];
    if (lane == 0) ws[wv] = v;
    __syncthreads();
    const int bpre = ws[0] + ws[1] + ws[2] + ws[3];

    const int i = blockIdx.x * 256 + t;
    if (i < NNODES) {
        const int o = offs[i] + bpre;
        offs[i]   = o;
        cursor[i] = o;
    }
    if (blockIdx.x == 0 && t == 0) offs[NNODES] = NEDGES;
}

// ---------------------------------------------------------------------------
// Scatter packed (tn | te<<16) pairs into CSR buckets
// ---------------------------------------------------------------------------
__global__ __launch_bounds__(256) void scatter_kernel(
    const int4* __restrict__ src4, const int4* __restrict__ dst4,
    const int* __restrict__ node_tokens, const int4* __restrict__ et4,
    int* __restrict__ cursor, uint_t* __restrict__ pairs)
{
    const int t = blockIdx.x * 256 + threadIdx.x;
    if (t >= NEDGES / 4) return;
    const int4 s = src4[t];
    const int4 d = dst4[t];
    const int4 te = et4[t];
    int p;
    p = atomicAdd(&cursor[d.x], 1);
    pairs[p] = (uint_t)node_tokens[s.x] | ((uint_t)te.x << 16);
    p = atomicAdd(&cursor[d.y], 1);
    pairs[p] = (uint_t)node_tokens[s.y] | ((uint_t)te.y << 16);
    p = atomicAdd(&cursor[d.z], 1);
    pairs[p] = (uint_t)node_tokens[s.z] | ((uint_t)te.z << 16);
    p = atomicAdd(&cursor[d.w], 1);
    pairs[p] = (uint_t)node_tokens[s.w] | ((uint_t)te.w << 16);
}

// ---------------------------------------------------------------------------
// Gather: one wave per node; even/odd edge split across half-waves.
// bf16 table rows (256 B): sublane sl loads ushort4 -> 4 output columns.
// f32 accumulate, shfl_xor(32) combine, one coalesced float4 row write.
// ---------------------------------------------------------------------------
__global__ __launch_bounds__(256) void gather_kernel(
    const ushort_t* __restrict__ t1, const ushort_t* __restrict__ t2,
    const int* __restrict__ offsets, const uint_t* __restrict__ pairs,
    float* __restrict__ outp)
{
    const int wid = (blockIdx.x * 256 + threadIdx.x) >> 6;
    if (wid >= NNODES) return;
    const int lane = threadIdx.x & 63;
    const int half = lane >> 5;
    const int sl   = lane & 31;

    const int beg = offsets[wid];
    const int end = offsets[wid + 1];

    float4 acc = {0.f, 0.f, 0.f, 0.f};
    for (int base = beg; base < end; base += 64) {
        const int m = min(64, end - base);
        uint_t pr = (lane < m) ? pairs[base + lane] : 0u;
        for (int j = half; j < m; j += 2) {
            const uint_t v = (uint_t)__shfl((int)pr, j);
            const int tn = (int)(v & 0xffffu);
            const int te = (int)(v >> 16);
            const ushort4 a  = ((const ushort4*)(t1 + (size_t)tn * D))[sl];
            const ushort4 bb = ((const ushort4*)(t2 + (size_t)te * D))[sl];
            acc.x = fmaf(bf2f(a.x), bf2f(bb.x), acc.x);
            acc.y = fmaf(bf2f(a.y), bf2f(bb.y), acc.y);
            acc.z = fmaf(bf2f(a.z), bf2f(bb.z), acc.z);
            acc.w = fmaf(bf2f(a.w), bf2f(bb.w), acc.w);
        }
    }
    acc.x += __shfl_xor(acc.x, 32);
    acc.y += __shfl_xor(acc.y, 32);
    acc.z += __shfl_xor(acc.z, 32);
    acc.w += __shfl_xor(acc.w, 32);
    if (half == 0)
        ((float4*)(outp + (size_t)wid * D))[sl] = acc;
}

extern "C" void kernel_launch(void* const* d_in, const int* in_sizes, int n_in,
                              void* d_out, int out_size, void* d_ws, size_t ws_size,
                              hipStream_t stream) {
    const float* emb = (const float*)d_in[0];
    const float* w1  = (const float*)d_in[1];
    const float* b1  = (const float*)d_in[2];
    const float* w2  = (const float*)d_in[3];
    const float* b2  = (const float*)d_in[4];
    const int* node_tokens = (const int*)d_in[5];
    const int* edge_tokens = (const int*)d_in[6];
    const int* src = (const int*)d_in[7];
    const int* dst = (const int*)d_in[8];
    float* out = (float*)d_out;

    // workspace layout (bytes)
    char* wsb = (char*)d_ws;
    ushort_t* t1     = (ushort_t*)(wsb);               //  8,192,000
    ushort_t* t2     = (ushort_t*)(wsb +  8192000);    //  8,192,000
    uint_t*   pairs  = (uint_t*)  (wsb + 16384000);    //  2,400,000
    int*      counts = (int*)     (wsb + 18784000);    //    200,000
    int*      offs   = (int*)     (wsb + 18984000);    //    200,004
    int*      cursor = (int*)     (wsb + 19184016);    //    200,000
    int*      btot   = (int*)     (wsb + 19384016);    //        784

    hipMemsetAsync(counts, 0, NNODES * sizeof(int), stream);

    // fused histogram + both table MLPs (blocks 0-499: w1, 500-999: w2)
    mlp_hist_kernel<<<1000, 256, 0, stream>>>(emb, w1, b1, w2, b2,
                                              t1, t2, dst, counts);

    const int nscan = (NNODES + 255) / 256;            // 196
    scan_phase1<<<nscan, 256, 0, stream>>>(counts, offs, btot);
    scan_phase2<<<nscan, 256, 0, stream>>>(btot, offs, cursor, nscan);
    scatter_kernel<<<(NEDGES / 4 + 255) / 256, 256, 0, stream>>>(
        (const int4*)src, (const int4*)dst, node_tokens,
        (const int4*)edge_tokens, cursor, pairs);

    gather_kernel<<<(NNODES + 3) / 4, 256, 0, stream>>>(t1, t2, offs, pairs, out);
}

// Round 8
// 207.048 us; speedup vs baseline: 3.7719x; 1.1725x over previous
//
#include <hip/hip_runtime.h>

#define VOCAB   32000
#define D       128
#define NNODES  50000
#define NEDGES  600000

typedef unsigned short ushort_t;
typedef unsigned int   uint_t;
typedef __attribute__((ext_vector_type(8))) __bf16 bf16x8;
typedef __attribute__((ext_vector_type(4))) float  f32x4;

__device__ __forceinline__ float bf2f(ushort_t u) {
    union { uint_t i; float f; } c; c.i = ((uint_t)u) << 16; return c.f;
}
__device__ __forceinline__ ushort_t f2bf(float f) {
    union { float f; uint_t i; } c; c.f = f;
    uint_t u = c.i;
    u += 0x7fff + ((u >> 16) & 1);            // round-to-nearest-even
    return (ushort_t)(u >> 16);
}

union PkAB { uint_t u[4]; bf16x8 v; };

// ---------------------------------------------------------------------------
// MFMA table MLP + fused dst-histogram.
// GEMM: [32000 x 128] emb  x  [128 x 256] (w1|w2)  + (b1|b2), relu, bf16 out.
// Block = 4 waves; wave wv owns 64 cols: wv 0,1 -> t1, wv 2,3 -> t2.
// B (w) fragments live in 64 VGPRs (loaded once, bf16); no LDS at all.
// Per wave: 2 M-tiles of 16 rows, 16 mfma_f32_16x16x32_bf16 per tile,
// acc initialized with bias (D = A*B + C), relu + bf16 store.
// Fragment layouts (guide-verified): A row=lane&15, k=(lane>>4)*8+e;
// B col=lane&15, k=(lane>>4)*8+e; D col=lane&15, row=(lane>>4)*4+reg.
// ---------------------------------------------------------------------------
__global__ __launch_bounds__(256) void mlp_mfma_hist_kernel(
    const float* __restrict__ emb,
    const float* __restrict__ w1, const float* __restrict__ b1,
    const float* __restrict__ w2, const float* __restrict__ b2,
    ushort_t* __restrict__ t1, ushort_t* __restrict__ t2,
    const int* __restrict__ dstv, int* __restrict__ counts)
{
    // histogram slice: 600 edges/block, hidden under the GEMM
    {
        const int base = blockIdx.x * (NEDGES / 1000);
        for (int i = base + threadIdx.x; i < base + NEDGES / 1000; i += 256)
            atomicAdd(&counts[dstv[i]], 1);
    }

    const int wv   = threadIdx.x >> 6;     // wave 0..3
    const int lane = threadIdx.x & 63;
    const int jcol = lane & 15;
    const int krow = (lane >> 4) * 8;      // 0,8,16,24

    const float* __restrict__ wsel = (wv >= 2) ? w2 : w1;
    const float* __restrict__ bsel = (wv >= 2) ? b2 : b1;
    ushort_t*    __restrict__ osel = (wv >= 2) ? t2 : t1;
    const int colT = (wv & 1) * 64;        // col base inside the table

    // B fragments [n][kk]: B[k = kk*32 + krow + e][col = colT + n*16 + jcol]
    PkAB bfrag[4][4];
    #pragma unroll
    for (int n = 0; n < 4; ++n) {
        const int c = colT + n * 16 + jcol;
        #pragma unroll
        for (int kk = 0; kk < 4; ++kk) {
            const int k0 = kk * 32 + krow;
            #pragma unroll
            for (int e = 0; e < 4; ++e) {
                const float lo = wsel[(size_t)(k0 + 2 * e)     * D + c];
                const float hi = wsel[(size_t)(k0 + 2 * e + 1) * D + c];
                bfrag[n][kk].u[e] = (uint_t)f2bf(lo) | ((uint_t)f2bf(hi) << 16);
            }
        }
    }

    float bval[4];
    #pragma unroll
    for (int n = 0; n < 4; ++n) bval[n] = bsel[colT + n * 16 + jcol];

    #pragma unroll
    for (int it = 0; it < 2; ++it) {
        const int rowbase = (it * 1000 + blockIdx.x) * 16;
        const float* __restrict__ aptr =
            emb + (size_t)(rowbase + jcol) * D + krow;

        // A fragments: A[row = rowbase + jcol][k = kk*32 + krow + e]
        PkAB afrag[4];
        #pragma unroll
        for (int kk = 0; kk < 4; ++kk) {
            const float4 xa = *(const float4*)(aptr + kk * 32);
            const float4 xb = *(const float4*)(aptr + kk * 32 + 4);
            afrag[kk].u[0] = (uint_t)f2bf(xa.x) | ((uint_t)f2bf(xa.y) << 16);
            afrag[kk].u[1] = (uint_t)f2bf(xa.z) | ((uint_t)f2bf(xa.w) << 16);
            afrag[kk].u[2] = (uint_t)f2bf(xb.x) | ((uint_t)f2bf(xb.y) << 16);
            afrag[kk].u[3] = (uint_t)f2bf(xb.z) | ((uint_t)f2bf(xb.w) << 16);
        }

        f32x4 acc[4];
        #pragma unroll
        for (int n = 0; n < 4; ++n)
            acc[n] = (f32x4){bval[n], bval[n], bval[n], bval[n]};

        #pragma unroll
        for (int kk = 0; kk < 4; ++kk) {
            #pragma unroll
            for (int n = 0; n < 4; ++n)
                acc[n] = __builtin_amdgcn_mfma_f32_16x16x32_bf16(
                    afrag[kk].v, bfrag[n][kk].v, acc[n], 0, 0, 0);
        }

        #pragma unroll
        for (int n = 0; n < 4; ++n) {
            #pragma unroll
            for (int j = 0; j < 4; ++j) {
                const int row = rowbase + (lane >> 4) * 4 + j;
                osel[(size_t)row * D + colT + n * 16 + jcol] =
                    f2bf(fmaxf(acc[n][j], 0.f));
            }
        }
    }
}

// ---------------------------------------------------------------------------
// Hierarchical scan (phase1: per-block excl scan + totals; phase2: add prefix)
// ---------------------------------------------------------------------------
__global__ __launch_bounds__(256) void scan_phase1(
    const int* __restrict__ counts,
    int* __restrict__ offs,
    int* __restrict__ btot)
{
    const int i    = blockIdx.x * 256 + threadIdx.x;
    const int lane = threadIdx.x & 63;
    const int wv   = threadIdx.x >> 6;

    const int v = (i < NNODES) ? counts[i] : 0;
    int inc = v;
    #pragma unroll
    for (int off = 1; off < 64; off <<= 1) {
        int u = __shfl_up(inc, off);
        if (lane >= off) inc += u;
    }
    __shared__ int wtot[4];
    if (lane == 63) wtot[wv] = inc;
    __syncthreads();
    int wpre = 0;
    #pragma unroll
    for (int k = 0; k < 3; ++k) if (k < wv) wpre += wtot[k];
    inc += wpre;
    if (i < NNODES) offs[i] = inc - v;
    if (threadIdx.x == 255) btot[blockIdx.x] = inc;
}

__global__ __launch_bounds__(256) void scan_phase2(
    const int* __restrict__ btot,
    int* __restrict__ offs,
    int* __restrict__ cursor,
    int nblocks)
{
    const int t    = threadIdx.x;
    const int lane = t & 63;
    const int wv   = t >> 6;

    int v = (t < blockIdx.x && t < nblocks) ? btot[t] : 0;
    #pragma unroll
    for (int off = 32; off > 0; off >>= 1) v += __shfl_xor(v, off);
    __shared__ int ws[4];
    if (lane == 0) ws[wv] = v;
    __syncthreads();
    const int bpre = ws[0] + ws[1] + ws[2] + ws[3];

    const int i = blockIdx.x * 256 + t;
    if (i < NNODES) {
        const int o = offs[i] + bpre;
        offs[i]   = o;
        cursor[i] = o;
    }
    if (blockIdx.x == 0 && t == 0) offs[NNODES] = NEDGES;
}

// ---------------------------------------------------------------------------
// Scatter packed (tn | te<<16) pairs into CSR buckets
// ---------------------------------------------------------------------------
__global__ __launch_bounds__(256) void scatter_kernel(
    const int4* __restrict__ src4, const int4* __restrict__ dst4,
    const int* __restrict__ node_tokens, const int4* __restrict__ et4,
    int* __restrict__ cursor, uint_t* __restrict__ pairs)
{
    const int t = blockIdx.x * 256 + threadIdx.x;
    if (t >= NEDGES / 4) return;
    const int4 s = src4[t];
    const int4 d = dst4[t];
    const int4 te = et4[t];
    int p;
    p = atomicAdd(&cursor[d.x], 1);
    pairs[p] = (uint_t)node_tokens[s.x] | ((uint_t)te.x << 16);
    p = atomicAdd(&cursor[d.y], 1);
    pairs[p] = (uint_t)node_tokens[s.y] | ((uint_t)te.y << 16);
    p = atomicAdd(&cursor[d.z], 1);
    pairs[p] = (uint_t)node_tokens[s.z] | ((uint_t)te.z << 16);
    p = atomicAdd(&cursor[d.w], 1);
    pairs[p] = (uint_t)node_tokens[s.w] | ((uint_t)te.w << 16);
}

// ---------------------------------------------------------------------------
// Gather: one wave per node; even/odd edge split across half-waves.
// bf16 table rows (256 B): sublane sl loads ushort4 -> 4 output columns.
// f32 accumulate, shfl_xor(32) combine, one coalesced float4 row write.
// ---------------------------------------------------------------------------
__global__ __launch_bounds__(256) void gather_kernel(
    const ushort_t* __restrict__ t1, const ushort_t* __restrict__ t2,
    const int* __restrict__ offsets, const uint_t* __restrict__ pairs,
    float* __restrict__ outp)
{
    const int wid = (blockIdx.x * 256 + threadIdx.x) >> 6;
    if (wid >= NNODES) return;
    const int lane = threadIdx.x & 63;
    const int half = lane >> 5;
    const int sl   = lane & 31;

    const int beg = offsets[wid];
    const int end = offsets[wid + 1];

    float4 acc = {0.f, 0.f, 0.f, 0.f};
    for (int base = beg; base < end; base += 64) {
        const int m = min(64, end - base);
        uint_t pr = (lane < m) ? pairs[base + lane] : 0u;
        for (int j = half; j < m; j += 2) {
            const uint_t v = (uint_t)__shfl((int)pr, j);
            const int tn = (int)(v & 0xffffu);
            const int te = (int)(v >> 16);
            const ushort4 a  = ((const ushort4*)(t1 + (size_t)tn * D))[sl];
            const ushort4 bb = ((const ushort4*)(t2 + (size_t)te * D))[sl];
            acc.x = fmaf(bf2f(a.x), bf2f(bb.x), acc.x);
            acc.y = fmaf(bf2f(a.y), bf2f(bb.y), acc.y);
            acc.z = fmaf(bf2f(a.z), bf2f(bb.z), acc.z);
            acc.w = fmaf(bf2f(a.w), bf2f(bb.w), acc.w);
        }
    }
    acc.x += __shfl_xor(acc.x, 32);
    acc.y += __shfl_xor(acc.y, 32);
    acc.z += __shfl_xor(acc.z, 32);
    acc.w += __shfl_xor(acc.w, 32);
    if (half == 0)
        ((float4*)(outp + (size_t)wid * D))[sl] = acc;
}

extern "C" void kernel_launch(void* const* d_in, const int* in_sizes, int n_in,
                              void* d_out, int out_size, void* d_ws, size_t ws_size,
                              hipStream_t stream) {
    const float* emb = (const float*)d_in[0];
    const float* w1  = (const float*)d_in[1];
    const float* b1  = (const float*)d_in[2];
    const float* w2  = (const float*)d_in[3];
    const float* b2  = (const float*)d_in[4];
    const int* node_tokens = (const int*)d_in[5];
    const int* edge_tokens = (const int*)d_in[6];
    const int* src = (const int*)d_in[7];
    const int* dst = (const int*)d_in[8];
    float* out = (float*)d_out;

    // workspace layout (bytes)
    char* wsb = (char*)d_ws;
    ushort_t* t1     = (ushort_t*)(wsb);               //  8,192,000
    ushort_t* t2     = (ushort_t*)(wsb +  8192000);    //  8,192,000
    uint_t*   pairs  = (uint_t*)  (wsb + 16384000);    //  2,400,000
    int*      counts = (int*)     (wsb + 18784000);    //    200,000
    int*      offs   = (int*)     (wsb + 18984000);    //    200,004
    int*      cursor = (int*)     (wsb + 19184016);    //    200,000
    int*      btot   = (int*)     (wsb + 19384016);    //        784

    hipMemsetAsync(counts, 0, NNODES * sizeof(int), stream);

    // fused histogram + both table MLPs via MFMA
    mlp_mfma_hist_kernel<<<1000, 256, 0, stream>>>(emb, w1, b1, w2, b2,
                                                   t1, t2, dst, counts);

    const int nscan = (NNODES + 255) / 256;            // 196
    scan_phase1<<<nscan, 256, 0, stream>>>(counts, offs, btot);
    scan_phase2<<<nscan, 256, 0, stream>>>(btot, offs, cursor, nscan);
    scatter_kernel<<<(NEDGES / 4 + 255) / 256, 256, 0, stream>>>(
        (const int4*)src, (const int4*)dst, node_tokens,
        (const int4*)edge_tokens, cursor, pairs);

    gather_kernel<<<(NNODES + 3) / 4, 256, 0, stream>>>(t1, t2, offs, pairs, out);
}